// Round 6
// baseline (200.994 us; speedup 1.0000x reference)
//
#include <hip/hip_runtime.h>

typedef unsigned long long u64;
typedef unsigned int u32;

#define G 512
#define T 128
#define P 256
#define B 512
#define NROWS 65536      /* G*T */
#define BIGBLOCKS 2048   /* big-pack blocks; 8 records per wave */

struct __align__(16) U64x2 { u64 x, y; };

// ---------------------------------------------------------------------------
// Ballot bit layout (identical for rows and pv; parity of AND is invariant
// under any shared bit permutation):
//   word j (j=0..3) of a 256-param row: bit L = param[4L + j].
// Row record = 8 u64 (64 B): psi words 0..3, phi words 4..7.
// codes[g*4 + {0,1,2,3}] = psi lo/hi, phi lo/hi term-const bits (identity in t).
// ---------------------------------------------------------------------------

__device__ __forceinline__ void store_rec8(u64* dst, u64 w0, u64 w1, u64 w2,
                                           u64 w3, u64 w4, u64 w5, u64 w6, u64 w7)
{
    U64x2* d = (U64x2*)dst;
    U64x2 a; a.x = w0; a.y = w1;
    U64x2 b; b.x = w2; b.y = w3;
    U64x2 c; c.x = w4; c.y = w5;
    U64x2 e; e.x = w6; e.y = w7;
    d[0] = a; d[1] = b; d[2] = c; d[3] = e;
}

// Packs everything. Blocks [0,2048): matrices. Blocks [2048,2080): pv + codes.
__global__ __launch_bounds__(256) void pack_all_kernel(
    const float* __restrict__ psi, const float* __restrict__ phi,
    const int* __restrict__ psi_c, const int* __restrict__ phi_c,
    const float* __restrict__ pvf,
    u64* __restrict__ rows, u64* __restrict__ codes, u64* __restrict__ pv)
{
    const int lane = threadIdx.x & 63;
    const int wave = threadIdx.x >> 6;

    if (blockIdx.x < BIGBLOCKS) {
        const int wid = blockIdx.x * 4 + wave;   // 0..8191
        const int r0  = wid * 8;                 // records [r0, r0+8)
        float4 A[8], Bf[8];
        #pragma unroll
        for (int k = 0; k < 8; ++k)
            A[k]  = *(const float4*)(psi + (size_t)(r0 + k) * P + lane * 4);
        #pragma unroll
        for (int k = 0; k < 8; ++k)
            Bf[k] = *(const float4*)(phi + (size_t)(r0 + k) * P + lane * 4);
        #pragma unroll
        for (int k = 0; k < 8; ++k) {
            u64 w0 = __ballot(A[k].x  != 0.0f);
            u64 w1 = __ballot(A[k].y  != 0.0f);
            u64 w2 = __ballot(A[k].z  != 0.0f);
            u64 w3 = __ballot(A[k].w  != 0.0f);
            u64 w4 = __ballot(Bf[k].x != 0.0f);
            u64 w5 = __ballot(Bf[k].y != 0.0f);
            u64 w6 = __ballot(Bf[k].z != 0.0f);
            u64 w7 = __ballot(Bf[k].w != 0.0f);
            if (lane == 0)
                store_rec8(rows + (size_t)(r0 + k) * 8,
                           w0, w1, w2, w3, w4, w5, w6, w7);
        }
    } else {
        const int wid2 = (blockIdx.x - BIGBLOCKS) * 4 + wave;  // 0..127
        float4 pf[4];
        int ip[8], iq[8];
        #pragma unroll
        for (int i = 0; i < 4; ++i)
            pf[i] = *(const float4*)(pvf + (size_t)(wid2 * 4 + i) * P + lane * 4);
        #pragma unroll
        for (int i = 0; i < 4; ++i) {
            int g = wid2 * 4 + i;
            ip[2 * i]     = psi_c[g * T + lane];
            ip[2 * i + 1] = psi_c[g * T + 64 + lane];
            iq[2 * i]     = phi_c[g * T + lane];
            iq[2 * i + 1] = phi_c[g * T + 64 + lane];
        }
        #pragma unroll
        for (int i = 0; i < 4; ++i) {
            int bt = wid2 * 4 + i;
            u64 w0 = __ballot(pf[i].x != 0.0f);
            u64 w1 = __ballot(pf[i].y != 0.0f);
            u64 w2 = __ballot(pf[i].z != 0.0f);
            u64 w3 = __ballot(pf[i].w != 0.0f);
            if (lane == 0) {
                U64x2* d = (U64x2*)(pv + (size_t)bt * 4);
                U64x2 a; a.x = w0; a.y = w1;
                U64x2 b; b.x = w2; b.y = w3;
                d[0] = a; d[1] = b;
            }
        }
        #pragma unroll
        for (int i = 0; i < 4; ++i) {
            int g = wid2 * 4 + i;
            u64 a0 = __ballot(ip[2 * i]     != 0);
            u64 a1 = __ballot(ip[2 * i + 1] != 0);
            u64 b0 = __ballot(iq[2 * i]     != 0);
            u64 b1 = __ballot(iq[2 * i + 1] != 0);
            if (lane == 0) {
                U64x2* d = (U64x2*)(codes + (size_t)g * 4);
                U64x2 a; a.x = a0; a.y = a1;
                U64x2 b; b.x = b0; b.y = b1;
                d[0] = a; d[1] = b;
            }
        }
    }
}

// 256-bit parity of (r[0..3] & v) given preloaded v words.
__device__ __forceinline__ unsigned par256(const u64* r, u64 v0, u64 v1,
                                           u64 v2, u64 v3)
{
    u64 m = (r[0] & v0) ^ (r[1] & v1) ^ (r[2] & v2) ^ (r[3] & v3);
    return (unsigned)__popcll(m);
}

// Main compute. Block = one g (pointer provably uniform -> scalar
// s_load_dwordx16 per term). Each thread owns TWO batches (b, b+256): the
// per-term row SGPRs feed 4 independent VALU chains (2 b x 2 term-streams),
// doubling VALU work per scalar load so SMEM latency is fully hidden.
// grid = G blocks of 256.
__global__ __launch_bounds__(256) void pi_main_kernel(
    const u64* __restrict__ rows,   // (g*T+t)*8 : psi u64 0..3, phi 4..7
    const u64* __restrict__ codes,  // g*4 : psi lo, psi hi, phi lo, phi hi
    const u64* __restrict__ pv,     // b*4
    float4*    __restrict__ out)
{
    const int g  = blockIdx.x;
    const int bx = threadIdx.x;          // batch pair (bx, bx+256)

    const u64* vx = pv + (size_t)bx * 4;
    const u64* vy = vx + 256 * 4;
    u64 x0 = vx[0], x1 = vx[1], x2 = vx[2], x3 = vx[3];
    u64 y0 = vy[0], y1 = vy[1], y2 = vy[2], y3 = vy[3];

    u64 pc0 = codes[g * 4 + 0], pc1 = codes[g * 4 + 1];   // uniform (scalar)
    u64 qc0 = codes[g * 4 + 2], qc1 = codes[g * 4 + 3];

    const u64* rA = rows + (size_t)g * (T * 8);           // terms 0..63
    const u64* rB = rA + 64 * 8;                          // terms 64..127

    unsigned ex0 = 0, ex1 = 0, ey0 = 0, ey1 = 0;
    #pragma unroll 4
    for (int t = 0; t < 64; ++t, rA += 8, rB += 8) {
        unsigned cp0 = (unsigned)(pc0 >> t), cq0 = (unsigned)(qc0 >> t);
        unsigned cp1 = (unsigned)(pc1 >> t), cq1 = (unsigned)(qc1 >> t);

        // stream A (term t), batch x and y
        {
            unsigned pax = par256(rA,     x0, x1, x2, x3);
            unsigned pbx = par256(rA + 4, x0, x1, x2, x3);
            ex0 ^= (pax ^ cp0) & (pbx ^ cq0);
            unsigned pay = par256(rA,     y0, y1, y2, y3);
            unsigned pby = par256(rA + 4, y0, y1, y2, y3);
            ey0 ^= (pay ^ cp0) & (pby ^ cq0);
        }
        // stream B (term t+64), batch x and y
        {
            unsigned pax = par256(rB,     x0, x1, x2, x3);
            unsigned pbx = par256(rB + 4, x0, x1, x2, x3);
            ex1 ^= (pax ^ cp1) & (pbx ^ cq1);
            unsigned pay = par256(rB,     y0, y1, y2, y3);
            unsigned pby = par256(rB + 4, y0, y1, y2, y3);
            ey1 ^= (pay ^ cp1) & (pby ^ cq1);
        }
    }
    unsigned ex = (ex0 ^ ex1) & 1u;
    unsigned ey = (ey0 ^ ey1) & 1u;

    out[(size_t)bx * G + g]          = make_float4(1.0f - 2.0f * (float)ex,
                                                   0.0f, 0.0f, 0.0f);
    out[(size_t)(bx + 256) * G + g]  = make_float4(1.0f - 2.0f * (float)ey,
                                                   0.0f, 0.0f, 0.0f);
}

extern "C" void kernel_launch(void* const* d_in, const int* in_sizes, int n_in,
                              void* d_out, int out_size, void* d_ws, size_t ws_size,
                              hipStream_t stream) {
    const int*   psi_const  = (const int*)  d_in[0];
    const float* psi_params = (const float*)d_in[1];
    const int*   phi_const  = (const int*)  d_in[2];
    const float* phi_params = (const float*)d_in[3];
    const float* param_vals = (const float*)d_in[4];

    // Workspace (u64 elements): rows 524288 (4 MiB) | codes 2048 | pv 2048
    u64* rows  = (u64*)d_ws;
    u64* codes = rows + (size_t)NROWS * 8;
    u64* pv    = codes + (size_t)G * 4;

    pack_all_kernel<<<BIGBLOCKS + 32, 256, 0, stream>>>(
        psi_params, phi_params, psi_const, phi_const, param_vals,
        rows, codes, pv);
    pi_main_kernel<<<G, 256, 0, stream>>>(rows, codes, pv, (float4*)d_out);
}